// Round 10
// baseline (1342.719 us; speedup 1.0000x reference)
//
#include <hip/hip_runtime.h>
#include <math.h>

// ---------------- problem constants ----------------
#define BB 2
#define HH 192
#define WW 192
#define NN 36864
#define CC 192
#define NHEAD 6
#define HD 32
#define MM 64
#define RC 10
#define GS 256
#define NG 144
#define HID 384
#define BN 73728

typedef unsigned short u16;
typedef __attribute__((ext_vector_type(8))) short short8;
typedef __attribute__((ext_vector_type(4))) float f32x4;

__device__ __forceinline__ float b2f(u16 u) { return __uint_as_float(((unsigned)u) << 16); }
__device__ __forceinline__ u16 f2b(float f) {
  unsigned v = __float_as_uint(f);
  return (u16)((v + 0x7fffu + ((v >> 16) & 1u)) >> 16);
}
__device__ __forceinline__ void up8(uint4 u, float* f) {
  f[0] = __uint_as_float(u.x << 16); f[1] = __uint_as_float(u.x & 0xffff0000u);
  f[2] = __uint_as_float(u.y << 16); f[3] = __uint_as_float(u.y & 0xffff0000u);
  f[4] = __uint_as_float(u.z << 16); f[5] = __uint_as_float(u.z & 0xffff0000u);
  f[6] = __uint_as_float(u.w << 16); f[7] = __uint_as_float(u.w & 0xffff0000u);
}
__device__ __forceinline__ float gelu_f(float v) {
  return 0.5f * v * (1.f + erff(v * 0.70710678118654752f));
}

// ---------------- zero scratch ----------------
__global__ void zero_kernel(int* __restrict__ p, int n) {
  int i = blockIdx.x * 256 + threadIdx.x;
  if (i < n) p[i] = 0;
}

// ---------------- LN1 fused with ATD q projection (fp32 path) ----------------
__global__ __launch_bounds__(256) void ln1_kernel(const float* __restrict__ x,
                                                  const float* __restrict__ g,
                                                  const float* __restrict__ be,
                                                  const float* __restrict__ wq,
                                                  const float* __restrict__ wqb,
                                                  u16* __restrict__ xnb,
                                                  float* __restrict__ qn) {
  int row = blockIdx.x * 4 + (threadIdx.x >> 6);
  int lane = threadIdx.x & 63;
  const float* p = x + (size_t)row * CC;
  float v0 = p[lane], v1 = p[lane + 64], v2 = p[lane + 128];
  float s = v0 + v1 + v2;
#pragma unroll
  for (int o = 32; o > 0; o >>= 1) s += __shfl_xor(s, o);
  float mu = s * (1.f / 192.f);
  float d0 = v0 - mu, d1 = v1 - mu, d2 = v2 - mu;
  float q2 = d0 * d0 + d1 * d1 + d2 * d2;
#pragma unroll
  for (int o = 32; o > 0; o >>= 1) q2 += __shfl_xor(q2, o);
  float rstd = rsqrtf(q2 * (1.f / 192.f) + 1e-5f);
  float xn0 = d0 * rstd * g[lane] + be[lane];
  float xn1 = d1 * rstd * g[lane + 64] + be[lane + 64];
  float xn2 = d2 * rstd * g[lane + 128] + be[lane + 128];
  u16* op = xnb + (size_t)row * CC;
  op[lane] = f2b(xn0); op[lane + 64] = f2b(xn1); op[lane + 128] = f2b(xn2);
  float qv[RC];
#pragma unroll
  for (int r = 0; r < RC; r++) {
    float t = xn0 * wq[lane * RC + r] + xn1 * wq[(lane + 64) * RC + r] + xn2 * wq[(lane + 128) * RC + r];
#pragma unroll
    for (int o = 32; o > 0; o >>= 1) t += __shfl_xor(t, o);
    qv[r] = t + wqb[r];
  }
  float nr = 0.f;
#pragma unroll
  for (int r = 0; r < RC; r++) nr += qv[r] * qv[r];
  float inv = 1.f / fmaxf(sqrtf(nr), 1e-12f);
  if (lane == 0) {
    float* qo = qn + (size_t)row * RC;
#pragma unroll
    for (int r = 0; r < RC; r++) qo[r] = qv[r] * inv;
  }
}

// ---------------- generic LN -> bf16 out ----------------
__global__ __launch_bounds__(256) void ln_kernel(const float* __restrict__ in,
                                                 u16* __restrict__ out,
                                                 const float* __restrict__ g,
                                                 const float* __restrict__ be) {
  int row = blockIdx.x * 4 + (threadIdx.x >> 6);
  int lane = threadIdx.x & 63;
  const float* p = in + (size_t)row * CC;
  float v0 = p[lane], v1 = p[lane + 64], v2 = p[lane + 128];
  float s = v0 + v1 + v2;
#pragma unroll
  for (int o = 32; o > 0; o >>= 1) s += __shfl_xor(s, o);
  float mu = s * (1.f / 192.f);
  float d0 = v0 - mu, d1 = v1 - mu, d2 = v2 - mu;
  float q2 = d0 * d0 + d1 * d1 + d2 * d2;
#pragma unroll
  for (int o = 32; o > 0; o >>= 1) q2 += __shfl_xor(q2, o);
  float rstd = rsqrtf(q2 * (1.f / 192.f) + 1e-5f);
  u16* op = out + (size_t)row * CC;
  op[lane]       = f2b(d0 * rstd * g[lane] + be[lane]);
  op[lane + 64]  = f2b(d1 * rstd * g[lane + 64] + be[lane + 64]);
  op[lane + 128] = f2b(d2 * rstd * g[lane + 128] + be[lane + 128]);
}

// ---------------- LDS-free direct MFMA GEMM ----------------
// A bf16 [M][K] row-major; Bt bf16 [N][K] (pre-transposed weights). 1 wave/block,
// 64x64 tile, no LDS, no barriers. B is L1/L2-hot (<=0.5MB, reused by all M-blocks);
// a wave's 4 quarter-groups consume full 64B lines of 16 A rows per load.
// EPI: 0 = bf16 store ; 1 = gelu+bf16 ; 2 = f32 RMW add
template <int EPI>
__global__ __launch_bounds__(64) void gemm_direct(const u16* __restrict__ A,
                                                  const u16* __restrict__ Bt,
                                                  const float* __restrict__ bias,
                                                  void* __restrict__ Cv,
                                                  int K, int Nn) {
  int lane = threadIdx.x;
  int l16 = lane & 15, l4 = lane >> 4;
  int m0 = blockIdx.x * 64, n0 = blockIdx.y * 64;
  f32x4 acc[4][4];
#pragma unroll
  for (int mi = 0; mi < 4; mi++)
#pragma unroll
    for (int ni = 0; ni < 4; ni++) acc[mi][ni] = (f32x4){0.f, 0.f, 0.f, 0.f};
  const u16* ap = A + (size_t)(m0 + l16) * K + l4 * 8;
  const u16* bp = Bt + (size_t)(n0 + l16) * K + l4 * 8;
#pragma unroll 2
  for (int kk = 0; kk < K; kk += 32) {
    short8 af[4], bf[4];
#pragma unroll
    for (int mi = 0; mi < 4; mi++)
      af[mi] = *reinterpret_cast<const short8*>(ap + (size_t)mi * 16 * K + kk);
#pragma unroll
    for (int ni = 0; ni < 4; ni++)
      bf[ni] = *reinterpret_cast<const short8*>(bp + (size_t)ni * 16 * K + kk);
#pragma unroll
    for (int mi = 0; mi < 4; mi++)
#pragma unroll
      for (int ni = 0; ni < 4; ni++)
        acc[mi][ni] = __builtin_amdgcn_mfma_f32_16x16x32_bf16(af[mi], bf[ni], acc[mi][ni], 0, 0, 0);
  }
#pragma unroll
  for (int ni = 0; ni < 4; ni++) {
    int col = n0 + ni * 16 + l16;
    float bv = bias[col];
#pragma unroll
    for (int mi = 0; mi < 4; mi++) {
#pragma unroll
      for (int r = 0; r < 4; r++) {
        size_t off = (size_t)(m0 + mi * 16 + 4 * l4 + r) * Nn + col;
        float c = acc[mi][ni][r] + bv;
        if constexpr (EPI == 2) {
          ((float*)Cv)[off] += c;
        } else {
          if constexpr (EPI == 1) c = gelu_f(c);
          ((u16*)Cv)[off] = f2b(c);
        }
      }
    }
  }
}

// ---------------- weight prep: bf16 B^T ----------------
__global__ void wprep1_kernel(const float* __restrict__ w, u16* __restrict__ bt) {
  int i = blockIdx.x * 256 + threadIdx.x;  // 110592 = k*576+n
  int k = i / 576, n = i % 576;
  bt[n * 192 + k] = f2b(w[i]);
}

__global__ void wprep2_kernel(const float* __restrict__ paca_w, const float* __restrict__ pwin_w,
                              const float* __restrict__ fc1_w, const float* __restrict__ fc2_w,
                              const float* __restrict__ paca_b, const float* __restrict__ pwin_b,
                              u16* __restrict__ bt, float* __restrict__ bcat) {
  int i = blockIdx.x * 256 + threadIdx.x;  // 73728
  {  // proj: Bt[n][k], n<192, k<384 (concat paca|pwin)
    int n = i / 384, k = i % 384;
    float v = (k < 192) ? paca_w[k * 192 + n] : pwin_w[(k - 192) * 192 + n];
    bt[i] = f2b(v);
  }
  {  // fc1: Bt[n][k], n<384, k<192
    int n = i / 192, k = i % 192;
    bt[73728 + i] = f2b(fc1_w[k * 384 + n]);
  }
  {  // fc2: Bt[n][k], n<192, k<384
    int n = i / 384, k = i % 384;
    bt[147456 + i] = f2b(fc2_w[k * 192 + n]);
  }
  if (i < 192) bcat[i] = paca_b[i] + pwin_b[i];
}

// ---------------- token-dictionary k/v projections (fp32, tiny) ----------------
__global__ __launch_bounds__(1024) void tdproj_kernel(const float* __restrict__ td,
                                                      const float* __restrict__ wk,
                                                      const float* __restrict__ wkb,
                                                      const float* __restrict__ wv,
                                                      const float* __restrict__ wvb,
                                                      const float* __restrict__ atd_scale,
                                                      float* __restrict__ knv,
                                                      float* __restrict__ vtd) {
  int b = blockIdx.x, tid = threadIdx.x;
  __shared__ float td_s[MM * CC];   // 48 KB
  __shared__ float k_s[MM][RC];
  const float* tdb = td + (size_t)b * MM * CC;
  for (int i = tid; i < MM * CC; i += 1024) td_s[i] = tdb[i];
  __syncthreads();
  for (int i = tid; i < MM * CC; i += 1024) {
    int m = i / CC, c = i % CC;
    float a = wvb[c];
    for (int r = 0; r < CC; r++) a += td_s[m * CC + r] * wv[r * CC + c];
    vtd[(size_t)b * MM * CC + i] = a;
  }
  for (int i = tid; i < MM * RC; i += 1024) {
    int m = i / RC, r = i % RC;
    float a = wkb[r];
    for (int c = 0; c < CC; c++) a += td_s[m * CC + c] * wk[c * RC + r];
    k_s[m][r] = a;
  }
  __syncthreads();
  if (tid < MM) {
    int m = tid;
    float nr = 0.f;
    for (int r = 0; r < RC; r++) nr += k_s[m][r] * k_s[m][r];
    float inv = 1.f / fmaxf(sqrtf(nr), 1e-12f);
    float sc = 1.f + fminf(fmaxf(atd_scale[m], 0.f), 1.f) * 4.1588830833596715f; // ln(64)
    for (int r = 0; r < RC; r++) knv[(size_t)b * MM * RC + m * RC + r] = k_s[m][r] * inv * sc;
  }
}

// ---------------- ATD cross attention (fp32): sim, tk_id, xacc = x + x_atd ----------------
__global__ __launch_bounds__(256, 2) void atd_kernel(const float* __restrict__ qn,
                                                     const float* __restrict__ x,
                                                     const float* __restrict__ knv,
                                                     const float* __restrict__ vtd,
                                                     float* __restrict__ sim,
                                                     int* __restrict__ tkid,
                                                     float* __restrict__ xacc) {
  __shared__ float v_s[MM][CC];   // 48 KB
  __shared__ float kn_s[MM][11];
  __shared__ float p_s[4][64];
  int tid = threadIdx.x;
  int b = (blockIdx.x * 64) / NN;
  float* vflat = &v_s[0][0];
  for (int i = tid; i < MM * CC; i += 256) vflat[i] = vtd[(size_t)b * MM * CC + i];
  for (int i = tid; i < MM * RC; i += 256) kn_s[i / RC][i % RC] = knv[(size_t)b * MM * RC + i];
  __syncthreads();
  int wave = tid >> 6, lane = tid & 63;
  for (int it = 0; it < 16; it++) {
    int tg = blockIdx.x * 64 + it * 4 + wave;
    const float* qr = qn + (size_t)tg * RC;
    float s = 0.f;
#pragma unroll
    for (int r = 0; r < RC; r++) s += qr[r] * kn_s[lane][r];
    float mx = s; int ai = lane;
#pragma unroll
    for (int o = 32; o > 0; o >>= 1) {
      float ov = __shfl_xor(mx, o); int oi = __shfl_xor(ai, o);
      if (ov > mx || (ov == mx && oi < ai)) { mx = ov; ai = oi; }
    }
    float e = __expf(s - mx);
    float sum = e;
#pragma unroll
    for (int o = 32; o > 0; o >>= 1) sum += __shfl_xor(sum, o);
    float p = e / sum;
    sim[(size_t)tg * MM + lane] = p;
    if (lane == 0) tkid[tg] = ai;
    p_s[wave][lane] = p;
    float a0 = 0.f, a1 = 0.f, a2 = 0.f;
#pragma unroll
    for (int m = 0; m < MM; m++) {
      float pm = p_s[wave][m];
      a0 += pm * v_s[m][lane];
      a1 += pm * v_s[m][lane + 64];
      a2 += pm * v_s[m][lane + 128];
    }
    const float* xr = x + (size_t)tg * CC;
    float* xo = xacc + (size_t)tg * CC;
    xo[lane]       = xr[lane]       + a0;
    xo[lane + 64]  = xr[lane + 64]  + a1;
    xo[lane + 128] = xr[lane + 128] + a2;
  }
}

// ---------------- stable counting sort of tk_id ----------------
__global__ void hist_kernel(const int* __restrict__ tkid, int* __restrict__ hist) {
  int i = blockIdx.x * 256 + threadIdx.x;
  if (i < BN) atomicAdd(&hist[(i / NN) * MM + tkid[i]], 1);
}

__global__ void scan_kernel(const int* __restrict__ hist, int* __restrict__ base) {
  int lane = threadIdx.x & 63, b = threadIdx.x >> 6;  // 128 threads
  int v = hist[b * MM + lane];
  int xx = v;
#pragma unroll
  for (int o = 1; o < 64; o <<= 1) { int t = __shfl_up(xx, o); if (lane >= o) xx += t; }
  base[b * MM + lane] = xx - v;
}

__global__ __launch_bounds__(256) void scatter_kernel(const int* __restrict__ tkid,
                                                      const int* __restrict__ base,
                                                      int* __restrict__ sort_idx) {
  int bk = blockIdx.x;
  int b = bk >> 6, key = bk & 63;
  int tid = threadIdx.x, wave = tid >> 6, lane = tid & 63;
  __shared__ int wtot[4];
  int offset = base[b * MM + key];
  const int* tk = tkid + (size_t)b * NN;
  for (int c0 = 0; c0 < NN; c0 += 256) {
    int i = c0 + tid;
    bool f = (tk[i] == key);
    unsigned long long mb = __ballot(f);
    int wpre = __popcll(mb & ((1ull << lane) - 1ull));
    if (lane == 0) wtot[wave] = __popcll(mb);
    __syncthreads();
    int pre = wpre;
#pragma unroll
    for (int w = 0; w < 4; w++) if (w < wave) pre += wtot[w];
    int tot = wtot[0] + wtot[1] + wtot[2] + wtot[3];
    if (f) sort_idx[(size_t)b * NN + offset + pre] = i;
    offset += tot;
    __syncthreads();
  }
}

// ---------------- rpb gather: TRANSPOSED [h][k][q] so C-in loads are float4 ----------------
__global__ void rpb_kernel(const int* __restrict__ rpi, const float* __restrict__ table,
                           float* __restrict__ rpbT) {
  int ij = blockIdx.x * 256 + threadIdx.x;  // 65536 = q*256 + k
  int q = ij >> 8, k = ij & 255;
  int idx = rpi[ij];
#pragma unroll
  for (int h = 0; h < NHEAD; h++) rpbT[h * 65536 + k * 256 + q] = table[idx * NHEAD + h];
}

// ---------------- MFMA attention, merged modes, full-S softmax ----------------
__global__ __launch_bounds__(256, 3) void attn_mfma_kernel(const u16* __restrict__ qkv,
                                                           const int* __restrict__ sort_idx,
                                                           const float* __restrict__ lgsc,
                                                           const float* __restrict__ rpbT,
                                                           const float* __restrict__ amask,
                                                           u16* __restrict__ ao) {
  __shared__ u16 Ks[GS][40];       // 20.5 KB
  __shared__ u16 Vt[HD][GS + 8];   // 16.9 KB, transposed
  __shared__ u16 Ps[4][16][72];    // 9.2 KB, per-wave per-qt P chunk
  int idx = blockIdx.x;
  int mode = 0;
  if (idx >= BB * NG * NHEAD) { mode = 1; idx -= BB * NG * NHEAD; }
  int h = idx % NHEAD; idx /= NHEAD;
  int g = idx % NG;    idx /= NG;
  int b = idx;
  int tid = threadIdx.x;
  int wave = tid >> 6, lane = tid & 63;
  int l16 = lane & 15, l4 = lane >> 4;
  const int* sp = sort_idx + (size_t)b * NN + g * GS;
  int wy = g / 12, wx = g % 12;

  auto tokof = [&](int i) -> int {
    if (mode == 0) return sp[i];
    int sy = (wy * 16 + (i >> 4) + 8) % 192;
    int sx = (wx * 16 + (i & 15) + 8) % 192;
    return sy * 192 + sx;
  };

#pragma unroll
  for (int it = 0; it < 4; it++) {
    int li = tid + it * 256;             // 0..1023
    int tok = li >> 2, q8 = (li & 3) * 8;
    size_t bas = ((size_t)b * NN + tokof(tok)) * 576 + h * HD + q8;
    uint4 kv = *reinterpret_cast<const uint4*>(qkv + bas + CC);
    *reinterpret_cast<uint4*>(&Ks[tok][q8]) = kv;
    ushort4 v0 = *reinterpret_cast<const ushort4*>(qkv + bas + 2 * CC);
    ushort4 v1 = *reinterpret_cast<const ushort4*>(qkv + bas + 2 * CC + 4);
    Vt[q8 + 0][tok] = v0.x; Vt[q8 + 1][tok] = v0.y;
    Vt[q8 + 2][tok] = v0.z; Vt[q8 + 3][tok] = v0.w;
    Vt[q8 + 4][tok] = v1.x; Vt[q8 + 5][tok] = v1.y;
    Vt[q8 + 6][tok] = v1.z; Vt[q8 + 7][tok] = v1.w;
  }
  float qscale = (mode == 0) ? __expf(fminf(lgsc[0], 4.605170185988092f))
                             : 0.17677669529663687f;
  bool bnd = (mode == 1) && ((wy == 11) || (wx == 11));
  __syncthreads();

  for (int qt = 0; qt < 4; qt++) {
    int q0 = wave * 64 + qt * 16 + 4 * l4;
    short8 qf;
    {
      int qrow = wave * 64 + qt * 16 + l16;
      size_t bas = ((size_t)b * NN + tokof(qrow)) * 576 + h * HD + l4 * 8;
      uint4 u = *reinterpret_cast<const uint4*>(qkv + bas);
      float f[8]; up8(u, f);
#pragma unroll
      for (int j = 0; j < 8; j++) ((u16*)&qf)[j] = f2b(f[j] * qscale);
    }
    f32x4 S[16];
#pragma unroll
    for (int kt = 0; kt < 16; kt++) {
      short8 kf = *reinterpret_cast<const short8*>(&Ks[kt * 16 + l16][l4 * 8]);
      f32x4 cin = (f32x4){0.f, 0.f, 0.f, 0.f};
      if (mode == 1)
        cin = *reinterpret_cast<const f32x4*>(rpbT + h * 65536 + (kt * 16 + l16) * 256 + q0);
      S[kt] = __builtin_amdgcn_mfma_f32_16x16x32_bf16(qf, kf, cin, 0, 0, 0);
    }
    if (bnd) {
#pragma unroll
      for (int kt = 0; kt < 16; kt++)
#pragma unroll
        for (int r = 0; r < 4; r++)
          S[kt][r] += amask[(size_t)g * 65536 + (size_t)(q0 + r) * 256 + kt * 16 + l16];
    }
#pragma unroll
    for (int r = 0; r < 4; r++) {
      float m = S[0][r];
#pragma unroll
      for (int kt = 1; kt < 16; kt++) m = fmaxf(m, S[kt][r]);
#pragma unroll
      for (int o = 1; o < 16; o <<= 1) m = fmaxf(m, __shfl_xor(m, o));
      float sum = 0.f;
#pragma unroll
      for (int kt = 0; kt < 16; kt++) {
        float p = __expf(S[kt][r] - m);
        S[kt][r] = p;
        sum += p;
      }
#pragma unroll
      for (int o = 1; o < 16; o <<= 1) sum += __shfl_xor(sum, o);
      float inv = 1.f / sum;
#pragma unroll
      for (int kt = 0; kt < 16; kt++) S[kt][r] *= inv;
    }
    f32x4 O0 = (f32x4){0.f, 0.f, 0.f, 0.f};
    f32x4 O1 = (f32x4){0.f, 0.f, 0.f, 0.f};
    for (int kc = 0; kc < 4; kc++) {
#pragma unroll
      for (int kt = 0; kt < 4; kt++)
#pragma unroll
        for (int r = 0; r < 4; r++)
          Ps[wave][4 * l4 + r][kt * 16 + l16] = f2b(S[kc * 4 + kt][r]);
#pragma unroll
      for (int s = 0; s < 2; s++) {
        short8 pa = *reinterpret_cast<const short8*>(&Ps[wave][l16][s * 32 + l4 * 8]);
        short8 v0 = *reinterpret_cast<const short8*>(&Vt[l16][kc * 64 + s * 32 + l4 * 8]);
        short8 v1 = *reinterpret_cast<const short8*>(&Vt[16 + l16][kc * 64 + s * 32 + l4 * 8]);
        O0 = __builtin_amdgcn_mfma_f32_16x16x32_bf16(pa, v0, O0, 0, 0, 0);
        O1 = __builtin_amdgcn_mfma_f32_16x16x32_bf16(pa, v1, O1, 0, 0, 0);
      }
    }
    int coff = mode ? CC : 0;
#pragma unroll
    for (int r = 0; r < 4; r++) {
      int tok = tokof(q0 + r);
      u16* ob = ao + ((size_t)b * NN + tok) * 384 + coff + h * HD;
      ob[l16]      = f2b(O0[r]);
      ob[16 + l16] = f2b(O1[r]);
    }
  }
}

// ---------------- depthwise 5x5 conv + gelu + residual — sliding-window, XCD-swizzled ----------------
__global__ __launch_bounds__(384) void dwconv_kernel(const u16* __restrict__ y2,
                                                     const float* __restrict__ dww,
                                                     const float* __restrict__ dwb,
                                                     u16* __restrict__ y2pc) {
  int c = threadIdx.x;
  int bid = blockIdx.x;
  int blk = (bid & 7) * (BB * HH * 2 / 8) + (bid >> 3);  // XCD swizzle: y-adjacent rows per XCD
  int half = blk & 1;
  int row = blk >> 1;
  int y = row % HH;
  int b = row / HH;
  int x0 = half * 96;
  float w[25];
#pragma unroll
  for (int j = 0; j < 25; j++) w[j] = dww[c * 25 + j];
  float bias = dwb[c];
  const u16* rp[5];
  bool rv[5];
#pragma unroll
  for (int dy = 0; dy < 5; dy++) {
    int yy = y + dy - 2;
    rv[dy] = (yy >= 0 && yy < HH);
    rp[dy] = y2 + ((size_t)b * NN + (size_t)(rv[dy] ? yy : y) * WW) * HID + c;
  }
  float win[5][5];
#pragma unroll
  for (int j = 0; j < 4; j++) {
    int col = x0 - 2 + j;
    constexpr int slotmap[4] = {3, 4, 0, 1};
    int slot = slotmap[j];
    bool cvld = (col >= 0);
    int colc = cvld ? col : 0;
#pragma unroll
    for (int dy = 0; dy < 5; dy++) {
      float v = b2f(rp[dy][(size_t)colc * HID]);
      win[dy][slot] = (cvld && rv[dy]) ? v : 0.f;
    }
  }
  u16* op = y2pc + ((size_t)b * NN + (size_t)y * WW) * HID + c;
  for (int tb = 0; tb < 100; tb += 5) {
#pragma unroll
    for (int p = 0; p < 5; p++) {
      int t = tb + p;
      int col = x0 + t + 2;
      const int slot = (p + 2) % 5;
      bool cvld = (col < WW);
      int colc = cvld ? col : (WW - 1);
#pragma unroll
      for (int dy = 0; dy < 5; dy++) {
        float v = b2f(rp[dy][(size_t)colc * HID]);
        win[dy][slot] = (cvld && rv[dy]) ? v : 0.f;
      }
      if (t < 96) {
        float acc = 0.f;
#pragma unroll
        for (int dy = 0; dy < 5; dy++)
#pragma unroll
          for (int dx = 0; dx < 5; dx++)
            acc += w[dy * 5 + dx] * win[dy][(p + 3 + dx) % 5];
        float gl = gelu_f(acc + bias);
        float res = win[2][p];
        op[(size_t)(x0 + t) * HID] = f2b(res + gl);
      }
    }
  }
}

// ---------------- td refinement ----------------
__global__ __launch_bounds__(256) void zsum_kernel(const float* __restrict__ sim,
                                                   float* __restrict__ Z) {
  int blk = blockIdx.x;
  int b = blk / NG;
  int n0 = (blk % NG) * 256;
  int tid = threadIdx.x, m = tid & 63, sub = tid >> 6;
  float a = 0.f;
  const float* sp = sim + ((size_t)b * NN + n0) * MM;
  for (int n = sub; n < 256; n += 4) a += __expf(sp[n * MM + m]);
  __shared__ float red[4][64];
  red[sub][m] = a;
  __syncthreads();
  if (tid < 64) atomicAdd(&Z[b * MM + m], red[0][m] + red[1][m] + red[2][m] + red[3][m]);
}

__global__ void invz_kernel(const float* __restrict__ Z, float* __restrict__ invZ) {
  int i = threadIdx.x;  // 128
  invZ[i] = 1.f / Z[i];
}

__global__ __launch_bounds__(192, 2) void tdacc_kernel(const float* __restrict__ sim,
                                                       const float* __restrict__ invZ,
                                                       const u16* __restrict__ ln3x,
                                                       float* __restrict__ tdacc) {
  __shared__ u16 w_s[256][64];  // 32 KB
  int blk = blockIdx.x;
  int b = blk / NG;
  int n0 = (blk % NG) * 256;
  int tid = threadIdx.x;
  const float* sp = sim + ((size_t)b * NN + n0) * MM;
  const float* iz = invZ + b * MM;
  for (int i = tid; i < 256 * 64; i += 192)
    w_s[i >> 6][i & 63] = f2b(__expf(sp[i]) * iz[i & 63]);
  __syncthreads();
  float acc[64];
#pragma unroll
  for (int m = 0; m < 64; m++) acc[m] = 0.f;
  const u16* lp = ln3x + ((size_t)b * NN + n0) * CC + tid;
  for (int n = 0; n < 256; n++) {
    float val = b2f(lp[(size_t)n * CC]);
    const uint4* wr = reinterpret_cast<const uint4*>(&w_s[n][0]);
#pragma unroll
    for (int c8 = 0; c8 < 8; c8++) {
      float f[8]; up8(wr[c8], f);
#pragma unroll
      for (int t = 0; t < 8; t++) acc[c8 * 8 + t] += f[t] * val;
    }
  }
  for (int m = 0; m < 64; m++) atomicAdd(&tdacc[((size_t)b * MM + m) * CC + tid], acc[m]);
}

__global__ void tdfin_kernel(const float* __restrict__ td, const float* __restrict__ sigma,
                             const float* __restrict__ tdacc, float* __restrict__ out) {
  int i = blockIdx.x * 256 + threadIdx.x;  // 24576
  if (i >= BB * MM * CC) return;
  int m = (i / CC) % MM;
  float s = 1.f / (1.f + __expf(-sigma[m]));
  out[i] = s * td[i] + (1.f - s) * tdacc[i];
}

// ---------------- workspace layout (bytes) ----------------
static constexpr size_t oQKV = 0;                                   // u16 BN*576 (later y2 bf16)
static constexpr size_t oXN  = oQKV + (size_t)BN * 576 * 2;         // u16 BN*192 (xn1/xn2/ln3x)
static constexpr size_t oAO  = oXN  + (size_t)BN * CC * 2;          // u16 BN*384 (aca|win; later y2pc)
static constexpr size_t oSIM = oAO  + (size_t)BN * 384 * 2;         // f32 BN*64
static constexpr size_t oQN  = oSIM + (size_t)BN * MM * 4;          // f32 BN*10
static constexpr size_t oRPB = oQN  + (size_t)BN * RC * 4;          // f32 6*65536 (rpbT; later BT2 bf16)
static constexpr size_t oVTD = oRPB + (size_t)6 * 65536 * 4;        // f32 BB*MM*CC
static constexpr size_t oKNV = oVTD + (size_t)BB * MM * CC * 4;     // f32 BB*MM*RC
static constexpr size_t oWC  = oKNV + (size_t)BB * MM * RC * 4;     // BTqkv u16 576*192 (221184B <= 294912B)
static constexpr size_t oBC  = oWC  + (size_t)384 * 192 * 4;        // f32 192 (pad to 1024)
static constexpr size_t oTK  = oBC  + 1024;                         // int BN
static constexpr size_t oSORT= oTK  + (size_t)BN * 4;               // int BN
static constexpr size_t oHIST= oSORT+ (size_t)BN * 4;               // int 128   } contiguous,
static constexpr size_t oBASE= oHIST+ 512;                          // int 128   } zeroed by
static constexpr size_t oZ   = oBASE+ 512;                          // f32 128   } zero_kernel
static constexpr size_t oTDA = oZ   + 512;                          // f32 BB*MM*CC }
static constexpr size_t oINV = oTDA + (size_t)BB * MM * CC * 4;     // f32 128
static constexpr size_t WS_NEEDED = oINV + 512;                     // ~194.4 MB

extern "C" void kernel_launch(void* const* d_in, const int* in_sizes, int n_in,
                              void* d_out, int out_size, void* d_ws, size_t ws_size,
                              hipStream_t stream) {
  if (ws_size < WS_NEEDED) return;  // diagnostic tripwire
  const float* x       = (const float*)d_in[0];
  const float* td      = (const float*)d_in[1];
  const int*   rpi     = (const int*)d_in[2];
  const float* amask   = (const float*)d_in[3];
  const float* n1g     = (const float*)d_in[6];
  const float* n1b     = (const float*)d_in[7];
  const float* n2g     = (const float*)d_in[8];
  const float* n2b     = (const float*)d_in[9];
  const float* n3g     = (const float*)d_in[10];
  const float* n3b     = (const float*)d_in[11];
  const float* wqkv_w  = (const float*)d_in[12];
  const float* wqkv_b  = (const float*)d_in[13];
  const float* wq_w    = (const float*)d_in[14];
  const float* wq_b    = (const float*)d_in[15];
  const float* wk_w    = (const float*)d_in[16];
  const float* wk_b    = (const float*)d_in[17];
  const float* wv_w    = (const float*)d_in[18];
  const float* wv_b    = (const float*)d_in[19];
  const float* atd_sc  = (const float*)d_in[20];
  const float* paca_w  = (const float*)d_in[21];
  const float* paca_b  = (const float*)d_in[22];
  const float* lgsc    = (const float*)d_in[23];
  const float* rpb_tab = (const float*)d_in[24];
  const float* pwin_w  = (const float*)d_in[25];
  const float* pwin_b  = (const float*)d_in[26];
  const float* fc1_w   = (const float*)d_in[27];
  const float* fc1_b   = (const float*)d_in[28];
  const float* dw_w    = (const float*)d_in[29];
  const float* dw_b    = (const float*)d_in[30];
  const float* fc2_w   = (const float*)d_in[31];
  const float* fc2_b   = (const float*)d_in[32];
  const float* sigma   = (const float*)d_in[33];
  float* out = (float*)d_out;
  char* wsb = (char*)d_ws;

  u16*   QKVb = (u16*)(wsb + oQKV);
  u16*   XNb  = (u16*)(wsb + oXN);
  u16*   AOb  = (u16*)(wsb + oAO);
  float* SIM  = (float*)(wsb + oSIM);
  float* QN   = (float*)(wsb + oQN);
  float* RPB  = (float*)(wsb + oRPB);
  u16*   BT2  = (u16*)(wsb + oRPB);   // proj|fc1|fc2 B^T, written AFTER attn consumed RPB
  float* VTD  = (float*)(wsb + oVTD);
  float* KNV  = (float*)(wsb + oKNV);
  u16*   BTQ  = (u16*)(wsb + oWC);    // qkv B^T
  float* BC   = (float*)(wsb + oBC);
  int*   TK   = (int*)(wsb + oTK);
  int*   SORT = (int*)(wsb + oSORT);
  int*   HIST = (int*)(wsb + oHIST);
  int*   BASE = (int*)(wsb + oBASE);
  float* Z    = (float*)(wsb + oZ);
  float* TDA  = (float*)(wsb + oTDA);
  float* INVZ = (float*)(wsb + oINV);

  zero_kernel<<<98, 256, 0, stream>>>(HIST, 24960);  // hist+base+Z+tdacc
  ln1_kernel<<<BN / 4, 256, 0, stream>>>(x, n1g, n1b, wq_w, wq_b, XNb, QN);
  tdproj_kernel<<<BB, 1024, 0, stream>>>(td, wk_w, wk_b, wv_w, wv_b, atd_sc, KNV, VTD);
  wprep1_kernel<<<432, 256, 0, stream>>>(wqkv_w, BTQ);
  gemm_direct<0><<<dim3(BN / 64, 9), 64, 0, stream>>>(XNb, BTQ, wqkv_b, QKVb, 192, 576);
  atd_kernel<<<BN / 64, 256, 0, stream>>>(QN, x, KNV, VTD, SIM, TK, out);
  hist_kernel<<<BN / 256, 256, 0, stream>>>(TK, HIST);
  scan_kernel<<<1, 128, 0, stream>>>(HIST, BASE);
  scatter_kernel<<<BB * MM, 256, 0, stream>>>(TK, BASE, SORT);
  rpb_kernel<<<256, 256, 0, stream>>>(rpi, rpb_tab, RPB);
  attn_mfma_kernel<<<2 * BB * NG * NHEAD, 256, 0, stream>>>(QKVb, SORT, lgsc, RPB, amask, AOb);
  wprep2_kernel<<<288, 256, 0, stream>>>(paca_w, pwin_w, fc1_w, fc2_w, paca_b, pwin_b, BT2, BC);
  gemm_direct<2><<<dim3(BN / 64, 3), 64, 0, stream>>>(AOb, BT2, BC, out, 384, 192);
  ln_kernel<<<BN / 4, 256, 0, stream>>>(out, XNb, n2g, n2b);
  gemm_direct<1><<<dim3(BN / 64, 6), 64, 0, stream>>>(XNb, BT2 + 73728, fc1_b, QKVb, 192, 384);
  dwconv_kernel<<<BB * HH * 2, 384, 0, stream>>>(QKVb, dw_w, dw_b, AOb);
  gemm_direct<2><<<dim3(BN / 64, 3), 64, 0, stream>>>(AOb, BT2 + 147456, fc2_b, out, 384, 192);
  ln_kernel<<<BN / 4, 256, 0, stream>>>(out, XNb, n3g, n3b);
  zsum_kernel<<<BB * NG, 256, 0, stream>>>(SIM, Z);
  invz_kernel<<<1, 128, 0, stream>>>(Z, INVZ);
  tdacc_kernel<<<BB * NG, 192, 0, stream>>>(SIM, INVZ, XNb, TDA);
  tdfin_kernel<<<96, 256, 0, stream>>>(td, sigma, TDA, out + (size_t)BN * CC);
}